// Round 1
// baseline (404.832 us; speedup 1.0000x reference)
//
#include <hip/hip_runtime.h>

#define VOCAB   32000
#define EMBED   2048
#define RANK    16
#define NADAPT  8
#define S_TOK   16384
#define T_TOK   128    // tokens per block
#define GRP     8      // base-gather prefetch group
#define ECHUNK  256    // e-elements per block (1 per thread)

// Each block: one 256-wide e-chunk, T_TOK tokens.
// B slices for ALL 8 adapters live in registers (8 x 4 float4 = 128 VGPR/thread),
// so B is read from global exactly once per block. Adapter select is a
// wave-uniform switch over compile-time register indices.
__global__ __launch_bounds__(256, 2)
void lora_embed_kernel(const int* __restrict__ input_ids,
                       const int* __restrict__ adapter_ids,
                       const float* __restrict__ weight,
                       const float* __restrict__ embA,
                       const float* __restrict__ embB,
                       float* __restrict__ out)
{
    const int tid    = threadIdx.x;
    const int echunk = blockIdx.x & 7;   // fast-varying: 8 e-chunks share weight rows via L3
    const int tchunk = blockIdx.x >> 3;  // 128 token chunks
    const int e      = echunk * ECHUNK + tid;
    const int t0     = tchunk * T_TOK;

    __shared__ int   ids_s[T_TOK];
    __shared__ int   ads_s[T_TOK];
    __shared__ float a_s[T_TOK][RANK];

    // ---- stage token ids / adapter ids (coalesced, once per block) ----
    if (tid < T_TOK) {
        int id = input_ids[t0 + tid];
        if (id > VOCAB - 1) id = 0;          // out-of-vocab mask -> 0
        ids_s[tid] = id;
        ads_s[tid] = adapter_ids[t0 + tid];
    }
    __syncthreads();

    // ---- stage LoRA-A vectors for all T_TOK tokens: 128x16 floats = 8 KiB ----
    for (int j = tid; j < T_TOK * RANK; j += 256) {
        const int i = j >> 4, r = j & 15;
        a_s[i][r] = embA[((long)ads_s[i] * VOCAB + ids_s[i]) * RANK + r];
    }

    // ---- stage B[ad][e][:] for all 8 adapters into registers ----
    float4 b[NADAPT][4];
    const float4* B4 = (const float4*)embB;
    #pragma unroll
    for (int ad = 0; ad < NADAPT; ++ad) {
        #pragma unroll
        for (int c = 0; c < 4; ++c)
            b[ad][c] = B4[((long)ad * EMBED + e) * 4 + c];
    }
    __syncthreads();

    // ---- main token loop: prefetch GRP base values, then compute ----
    for (int g = 0; g < T_TOK; g += GRP) {
        float basev[GRP];
        int   adg[GRP];
        #pragma unroll
        for (int u = 0; u < GRP; ++u) {
            const int id = __builtin_amdgcn_readfirstlane(ids_s[g + u]);
            adg[u]       = __builtin_amdgcn_readfirstlane(ads_s[g + u]);
            basev[u] = weight[(long)id * EMBED + e];   // coalesced 4B/lane gather
        }
        #pragma unroll
        for (int u = 0; u < GRP; ++u) {
            const int i = g + u;
            const float4 a0 = *(const float4*)&a_s[i][0];
            const float4 a1 = *(const float4*)&a_s[i][4];
            const float4 a2 = *(const float4*)&a_s[i][8];
            const float4 a3 = *(const float4*)&a_s[i][12];
            float acc = basev[u];
            switch (adg[u]) {
#define CASE(K) case K: \
                acc += a0.x*b[K][0].x + a0.y*b[K][0].y + a0.z*b[K][0].z + a0.w*b[K][0].w \
                     + a1.x*b[K][1].x + a1.y*b[K][1].y + a1.z*b[K][1].z + a1.w*b[K][1].w \
                     + a2.x*b[K][2].x + a2.y*b[K][2].y + a2.z*b[K][2].z + a2.w*b[K][2].w \
                     + a3.x*b[K][3].x + a3.y*b[K][3].y + a3.z*b[K][3].z + a3.w*b[K][3].w; \
                break;
                CASE(0) CASE(1) CASE(2) CASE(3) CASE(4) CASE(5) CASE(6) CASE(7)
#undef CASE
            }
            out[(long)(t0 + i) * EMBED + e] = acc;
        }
    }
}

extern "C" void kernel_launch(void* const* d_in, const int* in_sizes, int n_in,
                              void* d_out, int out_size, void* d_ws, size_t ws_size,
                              hipStream_t stream) {
    const int*   input_ids   = (const int*)d_in[0];
    const int*   adapter_ids = (const int*)d_in[1];
    const float* weight      = (const float*)d_in[2];
    const float* embA        = (const float*)d_in[3];
    const float* embB        = (const float*)d_in[4];
    float*       out         = (float*)d_out;

    // grid: 128 token-chunks x 8 e-chunks = 1024 blocks, 256 threads each
    dim3 grid((S_TOK / T_TOK) * (EMBED / ECHUNK));
    dim3 block(256);
    hipLaunchKernelGGL(lora_embed_kernel, grid, block, 0, stream,
                       input_ids, adapter_ids, weight, embA, embB, out);
}